// Round 3
// baseline (83.187 us; speedup 1.0000x reference)
//
#include <hip/hip_runtime.h>
#include <math.h>

// CircleLoss (m=1, GAMMA=1):
//   a_i = -|op - pc_i| * (pc_i - delta_p),  b_i = |nc_i - on| * (nc_i - delta_n)
//   loss = log(1 + (sum_i exp(a_i)) * (sum_i exp(b_i)))
// Stable online log-sum-exp; loss = softplus(Mp + log Sp + Mn + log Sn).
// Memory-bound streaming reduce: 402 MB read once.
// R2: 80.8 us @ 5.0 TB/s. This round: 2-row software pipeline (12 loads in
// flight, interleaved butterflies) to close the latency-exposure gap.

#define NEG_BIG (-1.0e30f)

__device__ __forceinline__ float margin_val(const void* p) {
    int iv = *(const int*)p;
    if (iv > -(1 << 23) && iv < (1 << 23)) return (float)iv;
    return *(const float*)p;
}

__device__ __forceinline__ float dot8(float4 a0, float4 a1, float4 b0, float4 b1) {
    return a0.x*b0.x + a0.y*b0.y + a0.z*b0.z + a0.w*b0.w
         + a1.x*b1.x + a1.y*b1.y + a1.z*b1.z + a1.w*b1.w;
}

__device__ __forceinline__ void lse_combine(float& m, float& s, float om, float os) {
    float M = fmaxf(m, om);
    s = s * expf(m - M) + os * expf(om - M);
    m = M;
}

__device__ __forceinline__ void lse_add(float& m, float& s, float a) {
    if (a > m) {
        s = s * expf(m - a) + 1.0f;
        m = a;
    } else {
        s += expf(a - m);
    }
}

__global__ __launch_bounds__(256) void circle_partial(
    const float* __restrict__ anchor,
    const float* __restrict__ positive,
    const float* __restrict__ negative,
    const void* __restrict__ margin_p,
    float4* __restrict__ ws,   // per-block (mp, sp, mn, sn)
    int N)
{
    const float m       = margin_val(margin_p);
    const float delta_p = 1.0f - m;
    const float delta_n = m;
    const float op      = 1.0f + m;
    const float on      = -m;

    const int lane          = threadIdx.x & 63;
    const int wid           = threadIdx.x >> 6;
    const int waves_per_blk = blockDim.x >> 6;
    const int gwave         = blockIdx.x * waves_per_blk + wid;
    const int nwaves        = gridDim.x * waves_per_blk;

    float mp = NEG_BIG, sp = 0.0f;
    float mn = NEG_BIG, sn = 0.0f;

    int row = gwave;
    // 2-row pipeline: 12 independent float4 loads in flight, then two
    // independent butterfly chains interleaved.
    for (; row + nwaves < N; row += 2 * nwaves) {
        const int rB = row + nwaves;
        const float4* aA = (const float4*)(anchor   + (size_t)row * 512);
        const float4* pA = (const float4*)(positive + (size_t)row * 512);
        const float4* nA = (const float4*)(negative + (size_t)row * 512);
        const float4* aB = (const float4*)(anchor   + (size_t)rB  * 512);
        const float4* pB = (const float4*)(positive + (size_t)rB  * 512);
        const float4* nB = (const float4*)(negative + (size_t)rB  * 512);

        float4 aA0 = aA[lane], aA1 = aA[lane + 64];
        float4 pA0 = pA[lane], pA1 = pA[lane + 64];
        float4 nA0 = nA[lane], nA1 = nA[lane + 64];
        float4 aB0 = aB[lane], aB1 = aB[lane + 64];
        float4 pB0 = pB[lane], pB1 = pB[lane + 64];
        float4 nB0 = nB[lane], nB1 = nB[lane + 64];

        float posA = dot8(aA0, aA1, pA0, pA1);
        float negA = dot8(aA0, aA1, nA0, nA1);
        float posB = dot8(aB0, aB1, pB0, pB1);
        float negB = dot8(aB0, aB1, nB0, nB1);

        #pragma unroll
        for (int off = 32; off > 0; off >>= 1) {
            posA += __shfl_xor(posA, off, 64);
            negA += __shfl_xor(negA, off, 64);
            posB += __shfl_xor(posB, off, 64);
            negB += __shfl_xor(negB, off, 64);
        }

        lse_add(mp, sp, -fabsf(op - posA) * (posA - delta_p));
        lse_add(mn, sn,  fabsf(negA - on) * (negA - delta_n));
        lse_add(mp, sp, -fabsf(op - posB) * (posB - delta_p));
        lse_add(mn, sn,  fabsf(negB - on) * (negB - delta_n));
    }
    // Tail (at most one row).
    if (row < N) {
        const float4* a4 = (const float4*)(anchor   + (size_t)row * 512);
        const float4* p4 = (const float4*)(positive + (size_t)row * 512);
        const float4* n4 = (const float4*)(negative + (size_t)row * 512);
        float4 a0 = a4[lane], a1 = a4[lane + 64];
        float4 p0 = p4[lane], p1 = p4[lane + 64];
        float4 n0 = n4[lane], n1 = n4[lane + 64];
        float pos = dot8(a0, a1, p0, p1);
        float neg = dot8(a0, a1, n0, n1);
        #pragma unroll
        for (int off = 32; off > 0; off >>= 1) {
            pos += __shfl_xor(pos, off, 64);
            neg += __shfl_xor(neg, off, 64);
        }
        lse_add(mp, sp, -fabsf(op - pos) * (pos - delta_p));
        lse_add(mn, sn,  fabsf(neg - on) * (neg - delta_n));
    }

    __shared__ float s_mp[8], s_sp[8], s_mn[8], s_sn[8];
    if (lane == 0) { s_mp[wid] = mp; s_sp[wid] = sp; s_mn[wid] = mn; s_sn[wid] = sn; }
    __syncthreads();
    if (threadIdx.x == 0) {
        float Mp = NEG_BIG, Sp = 0.0f, Mn = NEG_BIG, Sn = 0.0f;
        for (int i = 0; i < waves_per_blk; ++i) {
            lse_combine(Mp, Sp, s_mp[i], s_sp[i]);
            lse_combine(Mn, Sn, s_mn[i], s_sn[i]);
        }
        ws[blockIdx.x] = make_float4(Mp, Sp, Mn, Sn);  // plain overwrite
    }
}

__global__ __launch_bounds__(256) void circle_final(
    const float4* __restrict__ ws,
    int nblk,
    float* __restrict__ out)
{
    float mp = NEG_BIG, sp = 0.0f;
    float mn = NEG_BIG, sn = 0.0f;
    for (int i = threadIdx.x; i < nblk; i += blockDim.x) {
        float4 v = ws[i];
        lse_combine(mp, sp, v.x, v.y);
        lse_combine(mn, sn, v.z, v.w);
    }
    #pragma unroll
    for (int off = 32; off > 0; off >>= 1) {
        float omp = __shfl_xor(mp, off, 64);
        float osp = __shfl_xor(sp, off, 64);
        float omn = __shfl_xor(mn, off, 64);
        float osn = __shfl_xor(sn, off, 64);
        lse_combine(mp, sp, omp, osp);
        lse_combine(mn, sn, omn, osn);
    }
    __shared__ float s_mp[4], s_sp[4], s_mn[4], s_sn[4];
    const int lane = threadIdx.x & 63;
    const int wid  = threadIdx.x >> 6;
    if (lane == 0) { s_mp[wid] = mp; s_sp[wid] = sp; s_mn[wid] = mn; s_sn[wid] = sn; }
    __syncthreads();
    if (threadIdx.x == 0) {
        float Mp = NEG_BIG, Sp = 0.0f, Mn = NEG_BIG, Sn = 0.0f;
        for (int i = 0; i < 4; ++i) {
            lse_combine(Mp, Sp, s_mp[i], s_sp[i]);
            lse_combine(Mn, Sn, s_mn[i], s_sn[i]);
        }
        float L = Mp + Mn + logf(Sp) + logf(Sn);
        float loss = fmaxf(L, 0.0f) + log1pf(expf(-fabsf(L)));
        out[0] = loss;
    }
}

extern "C" void kernel_launch(void* const* d_in, const int* in_sizes, int n_in,
                              void* d_out, int out_size, void* d_ws, size_t ws_size,
                              hipStream_t stream) {
    const float* anchor   = (const float*)d_in[0];
    const float* positive = (const float*)d_in[1];
    const float* negative = (const float*)d_in[2];
    const void*  margin   = d_in[3];

    const int N = in_sizes[0] >> 9;  // D = 512 per reference

    int nblk = 2048;  // 8 blocks/CU; 32 waves/CU resident; 8 rows per wave
    const size_t need = (size_t)nblk * sizeof(float4);
    if (ws_size < need) nblk = (int)(ws_size / sizeof(float4));

    circle_partial<<<nblk, 256, 0, stream>>>(anchor, positive, negative, margin,
                                             (float4*)d_ws, N);
    circle_final<<<1, 256, 0, stream>>>((const float4*)d_ws, nblk, (float*)d_out);
}

// Round 4
// 81.573 us; speedup vs baseline: 1.0198x; 1.0198x over previous
//
#include <hip/hip_runtime.h>
#include <math.h>

// CircleLoss (m=1, GAMMA=1), stable online log-sum-exp:
//   loss = softplus(Mp + log Sp + Mn + log Sn)
// Memory-bound streaming reduce: 402 MB read once.
// R2: 80.8us @5.0TB/s (full-wave butterfly/row). R3: 2-row pipeline neutral.
// R4: 8 groups x 8 lanes per wave -- one row per group, 3-stage group
// butterfly per 8 rows (16x fewer DS ops), lse work 8x less. Tests whether
// the per-row reduce tail (not BW) was the governor.

#define NEG_BIG (-1.0e30f)

__device__ __forceinline__ float margin_val(const void* p) {
    int iv = *(const int*)p;
    if (iv > -(1 << 23) && iv < (1 << 23)) return (float)iv;
    return *(const float*)p;
}

// Combine two (max, scaled-sum) logsumexp states. Safe with NEG_BIG sentinels
// (expf(NEG_BIG - M) flushes to 0; s stays finite).
__device__ __forceinline__ void lse_combine(float& m, float& s, float om, float os) {
    float M = fmaxf(m, om);
    s = s * expf(m - M) + os * expf(om - M);
    m = M;
}

__global__ __launch_bounds__(256) void circle_partial(
    const float* __restrict__ anchor,
    const float* __restrict__ positive,
    const float* __restrict__ negative,
    const void* __restrict__ margin_p,
    float4* __restrict__ ws,   // per-block (mp, sp, mn, sn)
    int N)
{
    const float m       = margin_val(margin_p);
    const float delta_p = 1.0f - m;
    const float delta_n = m;
    const float op      = 1.0f + m;
    const float on      = -m;

    const int lane  = threadIdx.x & 63;
    const int wid   = threadIdx.x >> 6;
    const int g     = lane >> 3;   // group = row slot within batch (0..7)
    const int c     = lane & 7;    // chunk lane within group (0..7)
    const int gwave = blockIdx.x * 4 + wid;      // blockDim fixed at 256
    const int nwaves = gridDim.x * 4;

    float mp = NEG_BIG, sp = 0.0f;
    float mn = NEG_BIG, sn = 0.0f;

    const int nbatch = (N + 7) >> 3;   // batches of 8 rows
    for (int b = gwave; b < nbatch; b += nwaves) {
        const int row   = b * 8 + g;
        const bool valid = (row < N);

        float pos = 0.0f, neg = 0.0f;
        if (valid) {
            // Group g streams its whole row: 16 float4/lane, each instruction
            // reads 8x128B fully-used cache-line bursts per array.
            const float4* a4 = (const float4*)(anchor   + (size_t)row * 512);
            const float4* p4 = (const float4*)(positive + (size_t)row * 512);
            const float4* n4 = (const float4*)(negative + (size_t)row * 512);
            #pragma unroll 4
            for (int k = 0; k < 16; ++k) {
                float4 a = a4[c + 8 * k];
                float4 p = p4[c + 8 * k];
                float4 n = n4[c + 8 * k];
                pos += a.x*p.x + a.y*p.y + a.z*p.z + a.w*p.w;
                neg += a.x*n.x + a.y*n.y + a.z*n.z + a.w*n.w;
            }
        }

        // 3-stage butterfly within the 8-lane group -> row dot in all 8 lanes.
        #pragma unroll
        for (int off = 1; off < 8; off <<= 1) {
            pos += __shfl_xor(pos, off, 64);
            neg += __shfl_xor(neg, off, 64);
        }

        float ap = valid ? -fabsf(op - pos) * (pos - delta_p) : NEG_BIG;
        float an = valid ?  fabsf(neg - on) * (neg - delta_n) : NEG_BIG;
        lse_combine(mp, sp, ap, valid ? 1.0f : 0.0f);
        lse_combine(mn, sn, an, valid ? 1.0f : 0.0f);
    }

    // Merge across the 8 groups only (lane bits 3..5); within-group lanes hold
    // identical state, and we never combine same-group lanes (no double count).
    #pragma unroll
    for (int off = 8; off < 64; off <<= 1) {
        float omp = __shfl_xor(mp, off, 64);
        float osp = __shfl_xor(sp, off, 64);
        float omn = __shfl_xor(mn, off, 64);
        float osn = __shfl_xor(sn, off, 64);
        lse_combine(mp, sp, omp, osp);
        lse_combine(mn, sn, omn, osn);
    }

    __shared__ float s_mp[4], s_sp[4], s_mn[4], s_sn[4];
    if (lane == 0) { s_mp[wid] = mp; s_sp[wid] = sp; s_mn[wid] = mn; s_sn[wid] = sn; }
    __syncthreads();
    if (threadIdx.x == 0) {
        float Mp = NEG_BIG, Sp = 0.0f, Mn = NEG_BIG, Sn = 0.0f;
        for (int i = 0; i < 4; ++i) {
            lse_combine(Mp, Sp, s_mp[i], s_sp[i]);
            lse_combine(Mn, Sn, s_mn[i], s_sn[i]);
        }
        ws[blockIdx.x] = make_float4(Mp, Sp, Mn, Sn);  // plain overwrite
    }
}

__global__ __launch_bounds__(256) void circle_final(
    const float4* __restrict__ ws,
    int nblk,
    float* __restrict__ out)
{
    float mp = NEG_BIG, sp = 0.0f;
    float mn = NEG_BIG, sn = 0.0f;
    for (int i = threadIdx.x; i < nblk; i += blockDim.x) {
        float4 v = ws[i];
        lse_combine(mp, sp, v.x, v.y);
        lse_combine(mn, sn, v.z, v.w);
    }
    #pragma unroll
    for (int off = 32; off > 0; off >>= 1) {
        float omp = __shfl_xor(mp, off, 64);
        float osp = __shfl_xor(sp, off, 64);
        float omn = __shfl_xor(mn, off, 64);
        float osn = __shfl_xor(sn, off, 64);
        lse_combine(mp, sp, omp, osp);
        lse_combine(mn, sn, omn, osn);
    }
    __shared__ float s_mp[4], s_sp[4], s_mn[4], s_sn[4];
    const int lane = threadIdx.x & 63;
    const int wid  = threadIdx.x >> 6;
    if (lane == 0) { s_mp[wid] = mp; s_sp[wid] = sp; s_mn[wid] = mn; s_sn[wid] = sn; }
    __syncthreads();
    if (threadIdx.x == 0) {
        float Mp = NEG_BIG, Sp = 0.0f, Mn = NEG_BIG, Sn = 0.0f;
        for (int i = 0; i < 4; ++i) {
            lse_combine(Mp, Sp, s_mp[i], s_sp[i]);
            lse_combine(Mn, Sn, s_mn[i], s_sn[i]);
        }
        float L = Mp + Mn + logf(Sp) + logf(Sn);
        float loss = fmaxf(L, 0.0f) + log1pf(expf(-fabsf(L)));
        out[0] = loss;
    }
}

extern "C" void kernel_launch(void* const* d_in, const int* in_sizes, int n_in,
                              void* d_out, int out_size, void* d_ws, size_t ws_size,
                              hipStream_t stream) {
    const float* anchor   = (const float*)d_in[0];
    const float* positive = (const float*)d_in[1];
    const float* negative = (const float*)d_in[2];
    const void*  margin   = d_in[3];

    const int N = in_sizes[0] >> 9;  // D = 512 per reference

    int nblk = 2048;  // 8 blocks/CU; 32 waves/CU; one 8-row batch per wave
    const size_t need = (size_t)nblk * sizeof(float4);
    if (ws_size < need) nblk = (int)(ws_size / sizeof(float4));

    circle_partial<<<nblk, 256, 0, stream>>>(anchor, positive, negative, margin,
                                             (float4*)d_ws, N);
    circle_final<<<1, 256, 0, stream>>>((const float4*)d_ws, nblk, (float*)d_out);
}